// Round 1
// baseline (719.260 us; speedup 1.0000x reference)
//
#include <hip/hip_runtime.h>
#include <cfloat>
#include <cmath>

#define DI 128          // feature dim (= H*OUT)
#define NH 4            // heads
#define NEG_SLOPE 0.2f

// ---------------- CSR build (by dst) ----------------
__global__ void k_hist(const int* __restrict__ ei, int E, int N, int* __restrict__ counts) {
    int j = blockIdx.x * blockDim.x + threadIdx.x;
    int tot = E + N;
    if (j >= tot) return;
    int dst = (j < E) ? ei[E + j] : (j - E);   // self-loops appended
    atomicAdd(&counts[dst], 1);
}

__global__ __launch_bounds__(1024) void k_scan(const int* __restrict__ counts, int N,
                                               int* __restrict__ row_ptr, int* __restrict__ cursor) {
    __shared__ int wsum[16];
    __shared__ int carry_sh;
    int t = threadIdx.x, lane = t & 63, wv = t >> 6;
    if (t == 0) carry_sh = 0;
    __syncthreads();
    for (int base = 0; base < N; base += 1024) {
        int v = (base + t < N) ? counts[base + t] : 0;
        int incl = v;
        #pragma unroll
        for (int off = 1; off < 64; off <<= 1) {
            int y = __shfl_up(incl, off);
            if (lane >= off) incl += y;
        }
        if (lane == 63) wsum[wv] = incl;
        __syncthreads();
        if (wv == 0 && lane < 16) {
            int s = wsum[lane];
            #pragma unroll
            for (int off = 1; off < 16; off <<= 1) {
                int y = __shfl_up(s, off);
                if (lane >= off) s += y;
            }
            wsum[lane] = s;  // inclusive scan of wave sums
        }
        __syncthreads();
        int waveoff = (wv == 0) ? 0 : wsum[wv - 1];
        int carry = carry_sh;
        if (base + t < N) {
            int excl = carry + waveoff + incl - v;
            row_ptr[base + t] = excl;
            cursor[base + t]  = excl;
        }
        __syncthreads();
        if (t == 0) carry_sh = carry + wsum[15];
        __syncthreads();
    }
    if (t == 0) row_ptr[N] = carry_sh;
}

__global__ void k_scatter(const int* __restrict__ ei, int E, int N,
                          int* __restrict__ cursor, int* __restrict__ col_src) {
    int j = blockIdx.x * blockDim.x + threadIdx.x;
    int tot = E + N;
    if (j >= tot) return;
    int s, d;
    if (j < E) { s = ei[j]; d = ei[E + j]; } else { s = j - E; d = j - E; }
    int pos = atomicAdd(&cursor[d], 1);
    col_src[pos] = s;
}

// ---------------- h = x @ W  (+ fused attention halves) ----------------
// block = 256 threads = 4 waves; block computes 16 rows x 128 cols.
// wave w handles rows r0..r0+3; lane owns cols (2*lane, 2*lane+1).
__global__ __launch_bounds__(256) void k_gemm(
    const float* __restrict__ x, const float* __restrict__ W,
    const float* __restrict__ a_s, const float* __restrict__ a_d,
    float* __restrict__ h, float* __restrict__ al_s, float* __restrict__ al_d, int N)
{
    __shared__ float xs[16][DI];   // 8 KB
    int t = threadIdx.x;
    int rowBase = blockIdx.x * 16;
    {
        int idx = t * 8;
        int r = idx >> 7, c = idx & 127;
        int row = rowBase + r;
        float4 v0 = make_float4(0.f,0.f,0.f,0.f), v1 = v0;
        if (row < N) {
            const float4* p = reinterpret_cast<const float4*>(x + (size_t)row * DI + c);
            v0 = p[0]; v1 = p[1];
        }
        *reinterpret_cast<float4*>(&xs[r][c])     = v0;
        *reinterpret_cast<float4*>(&xs[r][c + 4]) = v1;
    }
    __syncthreads();

    int lane = t & 63, wave = t >> 6;
    int c0 = lane * 2;
    int r0 = wave * 4;
    float2 acc[4];
    #pragma unroll
    for (int rr = 0; rr < 4; ++rr) acc[rr] = make_float2(0.f, 0.f);

    for (int k = 0; k < DI; k += 4) {
        float2 w0 = *reinterpret_cast<const float2*>(W + (size_t)(k+0)*DI + c0);
        float2 w1 = *reinterpret_cast<const float2*>(W + (size_t)(k+1)*DI + c0);
        float2 w2 = *reinterpret_cast<const float2*>(W + (size_t)(k+2)*DI + c0);
        float2 w3 = *reinterpret_cast<const float2*>(W + (size_t)(k+3)*DI + c0);
        #pragma unroll
        for (int rr = 0; rr < 4; ++rr) {
            float4 xv = *reinterpret_cast<const float4*>(&xs[r0 + rr][k]);
            acc[rr].x = fmaf(xv.x, w0.x, acc[rr].x);
            acc[rr].y = fmaf(xv.x, w0.y, acc[rr].y);
            acc[rr].x = fmaf(xv.y, w1.x, acc[rr].x);
            acc[rr].y = fmaf(xv.y, w1.y, acc[rr].y);
            acc[rr].x = fmaf(xv.z, w2.x, acc[rr].x);
            acc[rr].y = fmaf(xv.z, w2.y, acc[rr].y);
            acc[rr].x = fmaf(xv.w, w3.x, acc[rr].x);
            acc[rr].y = fmaf(xv.w, w3.y, acc[rr].y);
        }
    }

    float2 as2 = *reinterpret_cast<const float2*>(a_s + c0);
    float2 ad2 = *reinterpret_cast<const float2*>(a_d + c0);
    int head = lane >> 4;
    #pragma unroll
    for (int rr = 0; rr < 4; ++rr) {
        int row = rowBase + r0 + rr;
        float ps = acc[rr].x * as2.x + acc[rr].y * as2.y;
        float pd = acc[rr].x * ad2.x + acc[rr].y * ad2.y;
        #pragma unroll
        for (int msk = 1; msk <= 8; msk <<= 1) {
            ps += __shfl_xor(ps, msk);
            pd += __shfl_xor(pd, msk);
        }
        if (row < N) {
            *reinterpret_cast<float2*>(h + (size_t)row * DI + c0) = acc[rr];
            if ((lane & 15) == 0) {
                al_s[row * NH + head] = ps;
                al_d[row * NH + head] = pd;
            }
        }
    }
}

// ---------------- segment softmax + aggregate (one wave per dst node) ----------------
__global__ __launch_bounds__(256) void k_agg(
    const float* __restrict__ h, const float* __restrict__ al_s, const float* __restrict__ al_d,
    const int* __restrict__ row_ptr, const int* __restrict__ col_src,
    const float* __restrict__ bias, float* __restrict__ out, int N)
{
    __shared__ float lds_p[4][256];
    __shared__ int   lds_s[4][64];
    int t = threadIdx.x;
    int wv = t >> 6, lane = t & 63;
    int n = blockIdx.x * 4 + wv;
    if (n >= N) return;

    int start = row_ptr[n], end = row_ptr[n + 1];
    int deg = end - start;               // >= 1 (self-loop)
    int h4  = lane & 3;                  // head for edge phases
    int sub = lane >> 2;                 // edge slot (0..15)
    float aldn = al_d[n * NH + h4];

    // Phase A: per-head max of leaky_relu logits
    float m = -FLT_MAX;
    for (int jb = 0; jb < deg; jb += 16) {
        int j = jb + sub;
        if (j < deg) {
            int s = col_src[start + j];
            float e = al_s[s * NH + h4] + aldn;
            e = (e > 0.f) ? e : NEG_SLOPE * e;
            m = fmaxf(m, e);
        }
    }
    #pragma unroll
    for (int msk = 4; msk <= 32; msk <<= 1) m = fmaxf(m, __shfl_xor(m, msk));

    // Phase B/C: exp + sum + weighted gather-accumulate, 64-edge chunks
    float ssum = 0.f;
    float2 acc = make_float2(0.f, 0.f);
    int myhead = lane >> 4;              // head of this lane's channels
    for (int cb = 0; cb < deg; cb += 64) {
        int cd = min(64, deg - cb);
        #pragma unroll
        for (int q = 0; q < 4; ++q) {
            int jl = q * 16 + sub;
            if (jl < cd) {
                int s = col_src[start + cb + jl];
                float e = al_s[s * NH + h4] + aldn;
                e = (e > 0.f) ? e : NEG_SLOPE * e;
                float p = __expf(e - m);
                ssum += p;
                lds_p[wv][jl * 4 + h4] = p;       // slot == lane: conflict-free
                if (h4 == 0) lds_s[wv][jl] = s;
            }
        }
        // wave-internal RAW on LDS: DS ops from one wave complete in order
        for (int jl = 0; jl < cd; ++jl) {
            int s = lds_s[wv][jl];
            float p = lds_p[wv][jl * 4 + myhead];
            float2 hv = *reinterpret_cast<const float2*>(h + (size_t)s * DI + lane * 2);
            acc.x = fmaf(p, hv.x, acc.x);
            acc.y = fmaf(p, hv.y, acc.y);
        }
    }
    #pragma unroll
    for (int msk = 4; msk <= 32; msk <<= 1) ssum += __shfl_xor(ssum, msk);
    float sdiv = __shfl(ssum, myhead);   // lane 'myhead' holds head myhead's sum

    float2 b2 = *reinterpret_cast<const float2*>(bias + lane * 2);
    float2 o;
    o.x = fmaxf(acc.x / sdiv + b2.x, 0.f);
    o.y = fmaxf(acc.y / sdiv + b2.y, 0.f);
    *reinterpret_cast<float2*>(out + (size_t)n * DI + lane * 2) = o;
}

// ---------------- graph mean-pool ----------------
__global__ void k_pool(const float* __restrict__ x, const int* __restrict__ batch,
                       int N, float* __restrict__ gout) {
    int g = blockIdx.x;
    int c = threadIdx.x;
    int lo = 0, hi = N;
    while (lo < hi) { int mid = (lo + hi) >> 1; if (batch[mid] < g) lo = mid + 1; else hi = mid; }
    int s0 = lo;
    lo = 0; hi = N;
    while (lo < hi) { int mid = (lo + hi) >> 1; if (batch[mid] < g + 1) lo = mid + 1; else hi = mid; }
    int s1 = lo;
    float acc = 0.f;
    for (int i = s0; i < s1; ++i) acc += x[(size_t)i * DI + c];
    float cnt = (float)(s1 - s0);
    gout[g * DI + c] = acc / fmaxf(cnt, 1.f);
}

extern "C" void kernel_launch(void* const* d_in, const int* in_sizes, int n_in,
                              void* d_out, int out_size, void* d_ws, size_t ws_size,
                              hipStream_t stream) {
    const float* x0    = (const float*)d_in[0];
    const int*   ei    = (const int*)  d_in[1];
    const int*   batch = (const int*)  d_in[2];
    const float* Ws    = (const float*)d_in[3];
    const float* a_src = (const float*)d_in[4];
    const float* a_dst = (const float*)d_in[5];
    const float* b     = (const float*)d_in[6];
    int N = in_sizes[2];
    int E = in_sizes[1] / 2;
    float* out = (float*)d_out;

    char* ws = (char*)d_ws;
    size_t off = 0;
    auto alloc = [&](size_t bytes) {
        void* p = ws + off;
        off += (bytes + 255) & ~(size_t)255;
        return p;
    };
    float* xbuf    = (float*)alloc((size_t)N * DI * 4);
    float* hbuf    = (float*)alloc((size_t)N * DI * 4);
    float* al_s    = (float*)alloc((size_t)N * NH * 4);
    float* al_d    = (float*)alloc((size_t)N * NH * 4);
    int*   counts  = (int*)  alloc((size_t)N * 4);
    int*   row_ptr = (int*)  alloc((size_t)(N + 1) * 4);
    int*   cursor  = (int*)  alloc((size_t)N * 4);
    int*   col_src = (int*)  alloc((size_t)(E + N) * 4);

    hipMemsetAsync(counts, 0, (size_t)N * 4, stream);
    int tot = E + N;
    k_hist   <<<(tot + 255) / 256, 256, 0, stream>>>(ei, E, N, counts);
    k_scan   <<<1, 1024, 0, stream>>>(counts, N, row_ptr, cursor);
    k_scatter<<<(tot + 255) / 256, 256, 0, stream>>>(ei, E, N, cursor, col_src);

    const float* xin = x0;
    for (int l = 0; l < 3; ++l) {
        const float* W   = Ws    + (size_t)l * DI * DI;
        const float* as_ = a_src + (size_t)l * NH * 32;
        const float* ad_ = a_dst + (size_t)l * NH * 32;
        const float* bl  = b     + (size_t)l * DI;
        k_gemm<<<(N + 15) / 16, 256, 0, stream>>>(xin, W, as_, ad_, hbuf, al_s, al_d, N);
        float* dst = (l == 2) ? out : xbuf;
        k_agg <<<(N + 3) / 4, 256, 0, stream>>>(hbuf, al_s, al_d, row_ptr, col_src, bl, dst, N);
        xin = xbuf;
    }
    k_pool<<<64, DI, 0, stream>>>(out, batch, N, out + (size_t)N * DI);
}

// Round 2
// 537.418 us; speedup vs baseline: 1.3384x; 1.3384x over previous
//
#include <hip/hip_runtime.h>
#include <cfloat>
#include <cmath>

#define DI 128          // feature dim (= H*OUT)
#define NH 4            // heads
#define NEG_SLOPE 0.2f

// ---------------- CSR build (by dst) ----------------
__global__ void k_hist(const int* __restrict__ ei, int E, int N, int* __restrict__ counts) {
    int j = blockIdx.x * blockDim.x + threadIdx.x;
    int tot = E + N;
    if (j >= tot) return;
    int dst = (j < E) ? ei[E + j] : (j - E);   // self-loops appended
    atomicAdd(&counts[dst], 1);
}

__global__ __launch_bounds__(1024) void k_scan(const int* __restrict__ counts, int N,
                                               int* __restrict__ row_ptr, int* __restrict__ cursor) {
    __shared__ int wsum[16];
    __shared__ int carry_sh;
    int t = threadIdx.x, lane = t & 63, wv = t >> 6;
    if (t == 0) carry_sh = 0;
    __syncthreads();
    for (int base = 0; base < N; base += 1024) {
        int v = (base + t < N) ? counts[base + t] : 0;
        int incl = v;
        #pragma unroll
        for (int off = 1; off < 64; off <<= 1) {
            int y = __shfl_up(incl, off);
            if (lane >= off) incl += y;
        }
        if (lane == 63) wsum[wv] = incl;
        __syncthreads();
        if (wv == 0 && lane < 16) {
            int s = wsum[lane];
            #pragma unroll
            for (int off = 1; off < 16; off <<= 1) {
                int y = __shfl_up(s, off);
                if (lane >= off) s += y;
            }
            wsum[lane] = s;  // inclusive scan of wave sums
        }
        __syncthreads();
        int waveoff = (wv == 0) ? 0 : wsum[wv - 1];
        int carry = carry_sh;
        if (base + t < N) {
            int excl = carry + waveoff + incl - v;
            row_ptr[base + t] = excl;
            cursor[base + t]  = excl;
        }
        __syncthreads();
        if (t == 0) carry_sh = carry + wsum[15];
        __syncthreads();
    }
    if (t == 0) row_ptr[N] = carry_sh;
}

__global__ void k_scatter(const int* __restrict__ ei, int E, int N,
                          int* __restrict__ cursor, int* __restrict__ col_src) {
    int j = blockIdx.x * blockDim.x + threadIdx.x;
    int tot = E + N;
    if (j >= tot) return;
    int s, d;
    if (j < E) { s = ei[j]; d = ei[E + j]; } else { s = j - E; d = j - E; }
    int pos = atomicAdd(&cursor[d], 1);
    col_src[pos] = s;
}

// ---------------- h = x @ W  (+ fused attention halves) ----------------
__global__ __launch_bounds__(256) void k_gemm(
    const float* __restrict__ x, const float* __restrict__ W,
    const float* __restrict__ a_s, const float* __restrict__ a_d,
    float* __restrict__ h, float* __restrict__ al_s, float* __restrict__ al_d, int N)
{
    __shared__ float xs[16][DI];   // 8 KB
    int t = threadIdx.x;
    int rowBase = blockIdx.x * 16;
    {
        int idx = t * 8;
        int r = idx >> 7, c = idx & 127;
        int row = rowBase + r;
        float4 v0 = make_float4(0.f,0.f,0.f,0.f), v1 = v0;
        if (row < N) {
            const float4* p = reinterpret_cast<const float4*>(x + (size_t)row * DI + c);
            v0 = p[0]; v1 = p[1];
        }
        *reinterpret_cast<float4*>(&xs[r][c])     = v0;
        *reinterpret_cast<float4*>(&xs[r][c + 4]) = v1;
    }
    __syncthreads();

    int lane = t & 63, wave = t >> 6;
    int c0 = lane * 2;
    int r0 = wave * 4;
    float2 acc[4];
    #pragma unroll
    for (int rr = 0; rr < 4; ++rr) acc[rr] = make_float2(0.f, 0.f);

    for (int k = 0; k < DI; k += 4) {
        float2 w0 = *reinterpret_cast<const float2*>(W + (size_t)(k+0)*DI + c0);
        float2 w1 = *reinterpret_cast<const float2*>(W + (size_t)(k+1)*DI + c0);
        float2 w2 = *reinterpret_cast<const float2*>(W + (size_t)(k+2)*DI + c0);
        float2 w3 = *reinterpret_cast<const float2*>(W + (size_t)(k+3)*DI + c0);
        #pragma unroll
        for (int rr = 0; rr < 4; ++rr) {
            float4 xv = *reinterpret_cast<const float4*>(&xs[r0 + rr][k]);
            acc[rr].x = fmaf(xv.x, w0.x, acc[rr].x);
            acc[rr].y = fmaf(xv.x, w0.y, acc[rr].y);
            acc[rr].x = fmaf(xv.y, w1.x, acc[rr].x);
            acc[rr].y = fmaf(xv.y, w1.y, acc[rr].y);
            acc[rr].x = fmaf(xv.z, w2.x, acc[rr].x);
            acc[rr].y = fmaf(xv.z, w2.y, acc[rr].y);
            acc[rr].x = fmaf(xv.w, w3.x, acc[rr].x);
            acc[rr].y = fmaf(xv.w, w3.y, acc[rr].y);
        }
    }

    float2 as2 = *reinterpret_cast<const float2*>(a_s + c0);
    float2 ad2 = *reinterpret_cast<const float2*>(a_d + c0);
    int head = lane >> 4;
    #pragma unroll
    for (int rr = 0; rr < 4; ++rr) {
        int row = rowBase + r0 + rr;
        float ps = acc[rr].x * as2.x + acc[rr].y * as2.y;
        float pd = acc[rr].x * ad2.x + acc[rr].y * ad2.y;
        #pragma unroll
        for (int msk = 1; msk <= 8; msk <<= 1) {
            ps += __shfl_xor(ps, msk);
            pd += __shfl_xor(pd, msk);
        }
        if (row < N) {
            *reinterpret_cast<float2*>(h + (size_t)row * DI + c0) = acc[rr];
            if ((lane & 15) == 0) {
                al_s[row * NH + head] = ps;
                al_d[row * NH + head] = pd;
            }
        }
    }
}

// ---------------- segment softmax + aggregate (one wave per dst node) ----------------
__global__ __launch_bounds__(256) void k_agg(
    const float* __restrict__ h, const float* __restrict__ al_s, const float* __restrict__ al_d,
    const int* __restrict__ row_ptr, const int* __restrict__ col_src,
    const float* __restrict__ bias, float* __restrict__ out, int N)
{
    __shared__ float lds_p[4][256];
    __shared__ int   lds_s[4][64];
    int t = threadIdx.x;
    int wv = t >> 6, lane = t & 63;
    int n = blockIdx.x * 4 + wv;
    if (n >= N) return;

    int start = row_ptr[n], end = row_ptr[n + 1];
    int deg = end - start;               // >= 1 (self-loop)
    int h4  = lane & 3;                  // head for edge phases
    int sub = lane >> 2;                 // edge slot (0..15)
    float aldn = al_d[n * NH + h4];

    // Phase A: per-head max of leaky_relu logits
    float m = -FLT_MAX;
    for (int jb = 0; jb < deg; jb += 16) {
        int j = jb + sub;
        if (j < deg) {
            int s = col_src[start + j];
            float e = al_s[s * NH + h4] + aldn;
            e = (e > 0.f) ? e : NEG_SLOPE * e;
            m = fmaxf(m, e);
        }
    }
    #pragma unroll
    for (int msk = 4; msk <= 32; msk <<= 1) m = fmaxf(m, __shfl_xor(m, msk));

    // Phase B/C: exp + sum + weighted gather-accumulate, 64-edge chunks
    float ssum = 0.f;
    float2 acc = make_float2(0.f, 0.f);
    int myhead = lane >> 4;              // head of this lane's channels
    for (int cb = 0; cb < deg; cb += 64) {
        int cd = min(64, deg - cb);
        #pragma unroll
        for (int q = 0; q < 4; ++q) {
            int jl = q * 16 + sub;
            if (jl < cd) {
                int s = col_src[start + cb + jl];
                float e = al_s[s * NH + h4] + aldn;
                e = (e > 0.f) ? e : NEG_SLOPE * e;
                float p = __expf(e - m);
                ssum += p;
                lds_p[wv][jl * 4 + h4] = p;       // slot == lane: conflict-free
                if (h4 == 0) lds_s[wv][jl] = s;
            }
        }
        for (int jl = 0; jl < cd; ++jl) {
            int s = lds_s[wv][jl];
            float p = lds_p[wv][jl * 4 + myhead];
            float2 hv = *reinterpret_cast<const float2*>(h + (size_t)s * DI + lane * 2);
            acc.x = fmaf(p, hv.x, acc.x);
            acc.y = fmaf(p, hv.y, acc.y);
        }
    }
    #pragma unroll
    for (int msk = 4; msk <= 32; msk <<= 1) ssum += __shfl_xor(ssum, msk);
    float sdiv = __shfl(ssum, myhead);

    float2 b2 = *reinterpret_cast<const float2*>(bias + lane * 2);
    float2 o;
    o.x = fmaxf(acc.x / sdiv + b2.x, 0.f);
    o.y = fmaxf(acc.y / sdiv + b2.y, 0.f);
    *reinterpret_cast<float2*>(out + (size_t)n * DI + lane * 2) = o;
}

// ---------------- graph mean-pool (two-phase, parallel) ----------------
// Phase 1: block covers 64 nodes x 128 ch (2 rows in flight). batch is sorted,
// so accumulate in a register and flush one atomicAdd per graph-boundary.
#define POOL_ROWS 64
__global__ __launch_bounds__(256) void k_pool_partial(
    const float* __restrict__ x, const int* __restrict__ batch,
    int N, float* __restrict__ gsum)
{
    int t = threadIdx.x;
    int c  = t & 127;
    int rh = t >> 7;                       // 0 or 1
    int base = blockIdx.x * POOL_ROWS;
    int lim = min(base + POOL_ROWS, N);
    int i = base + rh;
    if (i >= lim) return;
    int g_cur = batch[i];
    float acc = 0.f;
    for (; i < lim; i += 2) {
        int g = batch[i];
        if (g != g_cur) {
            atomicAdd(&gsum[(size_t)g_cur * DI + c], acc);
            acc = 0.f;
            g_cur = g;
        }
        acc += x[(size_t)i * DI + c];
    }
    atomicAdd(&gsum[(size_t)g_cur * DI + c], acc);
}

// Phase 2: divide by segment count (binary search in sorted batch).
__global__ void k_pool_final(const float* __restrict__ gsum, const int* __restrict__ batch,
                             int N, float* __restrict__ gout)
{
    int g = blockIdx.x;
    int c = threadIdx.x;
    int lo = 0, hi = N;
    while (lo < hi) { int mid = (lo + hi) >> 1; if (batch[mid] < g) lo = mid + 1; else hi = mid; }
    int s0 = lo;
    lo = 0; hi = N;
    while (lo < hi) { int mid = (lo + hi) >> 1; if (batch[mid] < g + 1) lo = mid + 1; else hi = mid; }
    int s1 = lo;
    float cnt = (float)(s1 - s0);
    gout[g * DI + c] = gsum[g * DI + c] / fmaxf(cnt, 1.f);
}

extern "C" void kernel_launch(void* const* d_in, const int* in_sizes, int n_in,
                              void* d_out, int out_size, void* d_ws, size_t ws_size,
                              hipStream_t stream) {
    const float* x0    = (const float*)d_in[0];
    const int*   ei    = (const int*)  d_in[1];
    const int*   batch = (const int*)  d_in[2];
    const float* Ws    = (const float*)d_in[3];
    const float* a_src = (const float*)d_in[4];
    const float* a_dst = (const float*)d_in[5];
    const float* b     = (const float*)d_in[6];
    int N = in_sizes[2];
    int E = in_sizes[1] / 2;
    int G = (out_size - N * DI) / DI;
    float* out = (float*)d_out;

    char* ws = (char*)d_ws;
    size_t off = 0;
    auto alloc = [&](size_t bytes) {
        void* p = ws + off;
        off += (bytes + 255) & ~(size_t)255;
        return p;
    };
    float* xbuf    = (float*)alloc((size_t)N * DI * 4);
    float* hbuf    = (float*)alloc((size_t)N * DI * 4);
    float* al_s    = (float*)alloc((size_t)N * NH * 4);
    float* al_d    = (float*)alloc((size_t)N * NH * 4);
    int*   counts  = (int*)  alloc((size_t)N * 4);
    int*   row_ptr = (int*)  alloc((size_t)(N + 1) * 4);
    int*   cursor  = (int*)  alloc((size_t)N * 4);
    int*   col_src = (int*)  alloc((size_t)(E + N) * 4);
    float* gsum    = (float*)alloc((size_t)G * DI * 4);

    hipMemsetAsync(counts, 0, (size_t)N * 4, stream);
    hipMemsetAsync(gsum,   0, (size_t)G * DI * 4, stream);
    int tot = E + N;
    k_hist   <<<(tot + 255) / 256, 256, 0, stream>>>(ei, E, N, counts);
    k_scan   <<<1, 1024, 0, stream>>>(counts, N, row_ptr, cursor);
    k_scatter<<<(tot + 255) / 256, 256, 0, stream>>>(ei, E, N, cursor, col_src);

    const float* xin = x0;
    for (int l = 0; l < 3; ++l) {
        const float* W   = Ws    + (size_t)l * DI * DI;
        const float* as_ = a_src + (size_t)l * NH * 32;
        const float* ad_ = a_dst + (size_t)l * NH * 32;
        const float* bl  = b     + (size_t)l * DI;
        k_gemm<<<(N + 15) / 16, 256, 0, stream>>>(xin, W, as_, ad_, hbuf, al_s, al_d, N);
        float* dst = (l == 2) ? out : xbuf;
        k_agg <<<(N + 3) / 4, 256, 0, stream>>>(hbuf, al_s, al_d, row_ptr, col_src, bl, dst, N);
        xin = xbuf;
    }
    k_pool_partial<<<(N + POOL_ROWS - 1) / POOL_ROWS, 256, 0, stream>>>(out, batch, N, gsum);
    k_pool_final  <<<G, DI, 0, stream>>>(gsum, batch, N, out + (size_t)N * DI);
}

// Round 3
// 493.861 us; speedup vs baseline: 1.4564x; 1.0882x over previous
//
#include <hip/hip_runtime.h>
#include <cfloat>
#include <cmath>

#define DI 128          // feature dim (= H*OUT)
#define NH 4            // heads
#define NEG_SLOPE 0.2f

// ---------------- CSR build (by dst) ----------------
__global__ void k_hist(const int* __restrict__ ei, int E, int N, int* __restrict__ counts) {
    int j = blockIdx.x * blockDim.x + threadIdx.x;
    int tot = E + N;
    if (j >= tot) return;
    int dst = (j < E) ? ei[E + j] : (j - E);   // self-loops appended
    atomicAdd(&counts[dst], 1);
}

__global__ __launch_bounds__(1024) void k_scan(const int* __restrict__ counts, int N,
                                               int* __restrict__ row_ptr, int* __restrict__ cursor) {
    __shared__ int wsum[16];
    __shared__ int carry_sh;
    int t = threadIdx.x, lane = t & 63, wv = t >> 6;
    if (t == 0) carry_sh = 0;
    __syncthreads();
    for (int base = 0; base < N; base += 1024) {
        int v = (base + t < N) ? counts[base + t] : 0;
        int incl = v;
        #pragma unroll
        for (int off = 1; off < 64; off <<= 1) {
            int y = __shfl_up(incl, off);
            if (lane >= off) incl += y;
        }
        if (lane == 63) wsum[wv] = incl;
        __syncthreads();
        if (wv == 0 && lane < 16) {
            int s = wsum[lane];
            #pragma unroll
            for (int off = 1; off < 16; off <<= 1) {
                int y = __shfl_up(s, off);
                if (lane >= off) s += y;
            }
            wsum[lane] = s;  // inclusive scan of wave sums
        }
        __syncthreads();
        int waveoff = (wv == 0) ? 0 : wsum[wv - 1];
        int carry = carry_sh;
        if (base + t < N) {
            int excl = carry + waveoff + incl - v;
            row_ptr[base + t] = excl;
            cursor[base + t]  = excl;
        }
        __syncthreads();
        if (t == 0) carry_sh = carry + wsum[15];
        __syncthreads();
    }
    if (t == 0) row_ptr[N] = carry_sh;
}

__global__ void k_scatter(const int* __restrict__ ei, int E, int N,
                          int* __restrict__ cursor, int* __restrict__ col_src) {
    int j = blockIdx.x * blockDim.x + threadIdx.x;
    int tot = E + N;
    if (j >= tot) return;
    int s, d;
    if (j < E) { s = ei[j]; d = ei[E + j]; } else { s = j - E; d = j - E; }
    int pos = atomicAdd(&cursor[d], 1);
    col_src[pos] = s;
}

// ---------------- h = x @ W  (+ fused attention halves) ----------------
// 512 threads = 8 waves. W (64KB) staged in LDS ONCE per block; block loops
// over 32-row x tiles. Wave handles 4 rows; lane owns cols (2*lane, 2*lane+1).
__global__ __launch_bounds__(512) void k_gemm(
    const float* __restrict__ x, const float* __restrict__ W,
    const float* __restrict__ a_s, const float* __restrict__ a_d,
    float* __restrict__ h, float* __restrict__ al_s, float* __restrict__ al_d,
    int N, int rows_per)
{
    __shared__ float wlds[DI * DI];   // 64 KB
    __shared__ float xs[32][DI];      // 16 KB
    int t = threadIdx.x;
    {
        const float4* Wv = reinterpret_cast<const float4*>(W);
        float4* wv = reinterpret_cast<float4*>(wlds);
        #pragma unroll
        for (int i = 0; i < 8; ++i) wv[t + i * 512] = Wv[t + i * 512];
    }
    int rbeg = blockIdx.x * rows_per;
    int rend = min(rbeg + rows_per, N);
    int lane = t & 63, wave = t >> 6;
    int c0 = lane * 2;
    int head = lane >> 4;
    float2 as2 = *reinterpret_cast<const float2*>(a_s + c0);
    float2 ad2 = *reinterpret_cast<const float2*>(a_d + c0);

    for (int base = rbeg; base < rend; base += 32) {
        __syncthreads();   // xs not in use (and W staged on first iter)
        {
            int idx = t * 8;
            int r = idx >> 7, c = idx & 127;
            int row = base + r;
            float4 v0 = make_float4(0.f,0.f,0.f,0.f), v1 = v0;
            if (row < N) {
                const float4* p = reinterpret_cast<const float4*>(x + (size_t)row * DI + c);
                v0 = p[0]; v1 = p[1];
            }
            *reinterpret_cast<float4*>(&xs[r][c])     = v0;
            *reinterpret_cast<float4*>(&xs[r][c + 4]) = v1;
        }
        __syncthreads();

        int r0 = wave * 4;
        float2 acc[4];
        #pragma unroll
        for (int rr = 0; rr < 4; ++rr) acc[rr] = make_float2(0.f, 0.f);

        for (int k = 0; k < DI; k += 4) {
            float2 w0 = *reinterpret_cast<const float2*>(&wlds[(k+0)*DI + c0]);
            float2 w1 = *reinterpret_cast<const float2*>(&wlds[(k+1)*DI + c0]);
            float2 w2 = *reinterpret_cast<const float2*>(&wlds[(k+2)*DI + c0]);
            float2 w3 = *reinterpret_cast<const float2*>(&wlds[(k+3)*DI + c0]);
            #pragma unroll
            for (int rr = 0; rr < 4; ++rr) {
                float4 xv = *reinterpret_cast<const float4*>(&xs[r0 + rr][k]);
                acc[rr].x = fmaf(xv.x, w0.x, acc[rr].x);
                acc[rr].y = fmaf(xv.x, w0.y, acc[rr].y);
                acc[rr].x = fmaf(xv.y, w1.x, acc[rr].x);
                acc[rr].y = fmaf(xv.y, w1.y, acc[rr].y);
                acc[rr].x = fmaf(xv.z, w2.x, acc[rr].x);
                acc[rr].y = fmaf(xv.z, w2.y, acc[rr].y);
                acc[rr].x = fmaf(xv.w, w3.x, acc[rr].x);
                acc[rr].y = fmaf(xv.w, w3.y, acc[rr].y);
            }
        }

        #pragma unroll
        for (int rr = 0; rr < 4; ++rr) {
            int row = base + r0 + rr;
            float ps = acc[rr].x * as2.x + acc[rr].y * as2.y;
            float pd = acc[rr].x * ad2.x + acc[rr].y * ad2.y;
            #pragma unroll
            for (int msk = 1; msk <= 8; msk <<= 1) {
                ps += __shfl_xor(ps, msk);
                pd += __shfl_xor(pd, msk);
            }
            if (row < rend) {
                *reinterpret_cast<float2*>(h + (size_t)row * DI + c0) = acc[rr];
                if ((lane & 15) == 0) {
                    al_s[row * NH + head] = ps;
                    al_d[row * NH + head] = pd;
                }
            }
        }
    }
}

// ---------------- segment softmax + aggregate (one wave per dst node) ----------------
// Gather phase: half-wave per edge-row, float4/lane (16B), 2 rows per wave-iter.
__global__ __launch_bounds__(256) void k_agg(
    const float* __restrict__ h, const float* __restrict__ al_s, const float* __restrict__ al_d,
    const int* __restrict__ row_ptr, const int* __restrict__ col_src,
    const float* __restrict__ bias, float* __restrict__ out, int N)
{
    __shared__ float lds_p[4][256];
    __shared__ int   lds_s[4][64];
    int t = threadIdx.x;
    int wv = t >> 6, lane = t & 63;
    int n = blockIdx.x * 4 + wv;
    if (n >= N) return;

    int start = row_ptr[n], end = row_ptr[n + 1];
    int deg = end - start;               // >= 1 (self-loop)
    int h4  = lane & 3;                  // head for edge phases
    int sub = lane >> 2;                 // edge slot (0..15)
    float aldn = al_d[n * NH + h4];

    // Phase A: per-head max of leaky_relu logits
    float m = -FLT_MAX;
    for (int jb = 0; jb < deg; jb += 16) {
        int j = jb + sub;
        if (j < deg) {
            int s = col_src[start + j];
            float e = al_s[s * NH + h4] + aldn;
            e = (e > 0.f) ? e : NEG_SLOPE * e;
            m = fmaxf(m, e);
        }
    }
    #pragma unroll
    for (int msk = 4; msk <= 32; msk <<= 1) m = fmaxf(m, __shfl_xor(m, msk));

    // Phase B/C: exp + sum + weighted gather-accumulate, 64-edge chunks
    int hw = lane >> 5;                  // half-wave (0/1)
    int cl = lane & 31;
    int c4 = cl * 4;                     // this lane's 4 channels
    int myhead = cl >> 3;                // head of those channels
    float ssum = 0.f;
    float4 acc = make_float4(0.f, 0.f, 0.f, 0.f);
    for (int cb = 0; cb < deg; cb += 64) {
        int cd = min(64, deg - cb);
        #pragma unroll
        for (int q = 0; q < 4; ++q) {
            int jl = q * 16 + sub;
            if (jl < cd) {
                int s = col_src[start + cb + jl];
                float e = al_s[s * NH + h4] + aldn;
                e = (e > 0.f) ? e : NEG_SLOPE * e;
                float p = __expf(e - m);
                ssum += p;
                lds_p[wv][jl * 4 + h4] = p;       // addr == 64q + lane: conflict-free
                if (h4 == 0) lds_s[wv][jl] = s;
            }
        }
        // wave-internal RAW on LDS (single-wave region, in-order DS)
        #pragma unroll 2
        for (int jl = hw; jl < cd; jl += 2) {
            int s = lds_s[wv][jl];
            float p = lds_p[wv][jl * 4 + myhead];
            float4 hv = *reinterpret_cast<const float4*>(h + (size_t)s * DI + c4);
            acc.x = fmaf(p, hv.x, acc.x);
            acc.y = fmaf(p, hv.y, acc.y);
            acc.z = fmaf(p, hv.z, acc.z);
            acc.w = fmaf(p, hv.w, acc.w);
        }
    }
    // combine the two half-wave partial sums (channels match across halves)
    acc.x += __shfl_xor(acc.x, 32);
    acc.y += __shfl_xor(acc.y, 32);
    acc.z += __shfl_xor(acc.z, 32);
    acc.w += __shfl_xor(acc.w, 32);
    #pragma unroll
    for (int msk = 4; msk <= 32; msk <<= 1) ssum += __shfl_xor(ssum, msk);
    float sdiv = __shfl(ssum, myhead);   // lane 'myhead' holds head myhead's sum

    if (hw == 0) {
        float4 b4 = *reinterpret_cast<const float4*>(bias + c4);
        float4 o;
        o.x = fmaxf(acc.x / sdiv + b4.x, 0.f);
        o.y = fmaxf(acc.y / sdiv + b4.y, 0.f);
        o.z = fmaxf(acc.z / sdiv + b4.z, 0.f);
        o.w = fmaxf(acc.w / sdiv + b4.w, 0.f);
        *reinterpret_cast<float4*>(out + (size_t)n * DI + c4) = o;
    }
}

// ---------------- graph mean-pool (two-phase, parallel) ----------------
#define POOL_ROWS 64
__global__ __launch_bounds__(256) void k_pool_partial(
    const float* __restrict__ x, const int* __restrict__ batch,
    int N, float* __restrict__ gsum)
{
    int t = threadIdx.x;
    int c  = t & 127;
    int rh = t >> 7;                       // 0 or 1
    int base = blockIdx.x * POOL_ROWS;
    int lim = min(base + POOL_ROWS, N);
    int i = base + rh;
    if (i >= lim) return;
    int g_cur = batch[i];
    float acc = 0.f;
    for (; i < lim; i += 2) {
        int g = batch[i];
        if (g != g_cur) {
            atomicAdd(&gsum[(size_t)g_cur * DI + c], acc);
            acc = 0.f;
            g_cur = g;
        }
        acc += x[(size_t)i * DI + c];
    }
    atomicAdd(&gsum[(size_t)g_cur * DI + c], acc);
}

__global__ void k_pool_final(const float* __restrict__ gsum, const int* __restrict__ batch,
                             int N, float* __restrict__ gout)
{
    int g = blockIdx.x;
    int c = threadIdx.x;
    int lo = 0, hi = N;
    while (lo < hi) { int mid = (lo + hi) >> 1; if (batch[mid] < g) lo = mid + 1; else hi = mid; }
    int s0 = lo;
    lo = 0; hi = N;
    while (lo < hi) { int mid = (lo + hi) >> 1; if (batch[mid] < g + 1) lo = mid + 1; else hi = mid; }
    int s1 = lo;
    float cnt = (float)(s1 - s0);
    gout[g * DI + c] = gsum[g * DI + c] / fmaxf(cnt, 1.f);
}

extern "C" void kernel_launch(void* const* d_in, const int* in_sizes, int n_in,
                              void* d_out, int out_size, void* d_ws, size_t ws_size,
                              hipStream_t stream) {
    const float* x0    = (const float*)d_in[0];
    const int*   ei    = (const int*)  d_in[1];
    const int*   batch = (const int*)  d_in[2];
    const float* Ws    = (const float*)d_in[3];
    const float* a_src = (const float*)d_in[4];
    const float* a_dst = (const float*)d_in[5];
    const float* b     = (const float*)d_in[6];
    int N = in_sizes[2];
    int E = in_sizes[1] / 2;
    int G = (out_size - N * DI) / DI;
    float* out = (float*)d_out;

    char* ws = (char*)d_ws;
    size_t off = 0;
    auto alloc = [&](size_t bytes) {
        void* p = ws + off;
        off += (bytes + 255) & ~(size_t)255;
        return p;
    };
    float* xbuf    = (float*)alloc((size_t)N * DI * 4);
    float* hbuf    = (float*)alloc((size_t)N * DI * 4);
    float* al_s    = (float*)alloc((size_t)N * NH * 4);
    float* al_d    = (float*)alloc((size_t)N * NH * 4);
    int*   counts  = (int*)  alloc((size_t)N * 4);
    int*   row_ptr = (int*)  alloc((size_t)(N + 1) * 4);
    int*   cursor  = (int*)  alloc((size_t)N * 4);
    int*   col_src = (int*)  alloc((size_t)(E + N) * 4);
    float* gsum    = (float*)alloc((size_t)G * DI * 4);

    hipMemsetAsync(counts, 0, (size_t)N * 4, stream);
    hipMemsetAsync(gsum,   0, (size_t)G * DI * 4, stream);
    int tot = E + N;
    k_hist   <<<(tot + 255) / 256, 256, 0, stream>>>(ei, E, N, counts);
    k_scan   <<<1, 1024, 0, stream>>>(counts, N, row_ptr, cursor);
    k_scatter<<<(tot + 255) / 256, 256, 0, stream>>>(ei, E, N, cursor, col_src);

    const int GEMM_BLOCKS = 512;
    int rows_per = (N + GEMM_BLOCKS - 1) / GEMM_BLOCKS;

    const float* xin = x0;
    for (int l = 0; l < 3; ++l) {
        const float* W   = Ws    + (size_t)l * DI * DI;
        const float* as_ = a_src + (size_t)l * NH * 32;
        const float* ad_ = a_dst + (size_t)l * NH * 32;
        const float* bl  = b     + (size_t)l * DI;
        k_gemm<<<GEMM_BLOCKS, 512, 0, stream>>>(xin, W, as_, ad_, hbuf, al_s, al_d, N, rows_per);
        float* dst = (l == 2) ? out : xbuf;
        k_agg <<<(N + 3) / 4, 256, 0, stream>>>(hbuf, al_s, al_d, row_ptr, col_src, bl, dst, N);
        xin = xbuf;
    }
    k_pool_partial<<<(N + POOL_ROWS - 1) / POOL_ROWS, 256, 0, stream>>>(out, batch, N, gsum);
    k_pool_final  <<<G, DI, 0, stream>>>(gsum, batch, N, out + (size_t)N * DI);
}